// Round 2
// baseline (335.383 us; speedup 1.0000x reference)
//
#include <hip/hip_runtime.h>

typedef _Float16 f16;
typedef _Float16 half8 __attribute__((ext_vector_type(8)));
typedef _Float16 half4 __attribute__((ext_vector_type(4)));
typedef float f32x4 __attribute__((ext_vector_type(4)));

#define BTOT 65536

// ---------------- workspace layout (bytes) ----------------
static const size_t OFF_FLAT = 0;
static const size_t SZ_FLAT  = (size_t)BTOT * 768 * 2;        // f16 [B][768]
static const size_t OFF_WIT  = OFF_FLAT + SZ_FLAT;            // f16 [256][768]
static const size_t SZ_WIT   = (size_t)256 * 768 * 2;
static const size_t SZ_WT128 = (size_t)208 * 128 * 2;         // 13 tiles * 16 rows
static const size_t SZ_WT64  = (size_t)144 * 64 * 2;          // 9 tiles * 16 rows
static const size_t OFF_WT0  = OFF_WIT + SZ_WIT;
static const size_t OFF_WT1  = OFF_WT0 + SZ_WT128;
static const size_t OFF_WT2  = OFF_WT1 + SZ_WT64;
static const size_t OFF_WT3  = OFF_WT2 + SZ_WT128;
static const size_t OFF_CO   = OFF_WT3 + SZ_WT64;             // f32 [4][64]
static const size_t OFF_C    = OFF_CO + 256 * 4;              // f32 [4]

// =============== weight fusion: wT[n][k] (f16), co, c ===============
// n<D: (Wq WkT)[k][n]/sqrt(D) ; n<D+64: (Wv wo)[k][n-D] ; n=D+64: (Wq bk)[k]/sqrt(D)
// n=D+65: (Wk bq)[k]/sqrt(D) ; else 0.  co = bv wo + bo ; c = bq.bk/sqrt(D)
__global__ __launch_bounds__(256) void pk_fuse(
    const float* __restrict__ wq0, const float* __restrict__ bq0, const float* __restrict__ wo0, const float* __restrict__ bo0,
    const float* __restrict__ wq1, const float* __restrict__ bq1, const float* __restrict__ wo1, const float* __restrict__ bo1,
    const float* __restrict__ wq2, const float* __restrict__ bq2, const float* __restrict__ wo2, const float* __restrict__ bo2,
    const float* __restrict__ wq3, const float* __restrict__ bq3, const float* __restrict__ wo3, const float* __restrict__ bo3,
    f16* __restrict__ wT0, f16* __restrict__ wT1, f16* __restrict__ wT2, f16* __restrict__ wT3,
    float* __restrict__ coAll, float* __restrict__ cAll)
{
    const int g = blockIdx.y;
    const float* wqkv; const float* bqkv; const float* wo; const float* bo; f16* wT; int D;
    switch (g) {
        case 0:  wqkv = wq0; bqkv = bq0; wo = wo0; bo = bo0; wT = wT0; D = 128; break;
        case 1:  wqkv = wq1; bqkv = bq1; wo = wo1; bo = bo1; wT = wT1; D = 64;  break;
        case 2:  wqkv = wq2; bqkv = bq2; wo = wo2; bo = bo2; wT = wT2; D = 128; break;
        default: wqkv = wq3; bqkv = bq3; wo = wo3; bo = bo3; wT = wT3; D = 64;  break;
    }
    const int sh = (D == 128) ? 7 : 6;
    const int NT = (D + 81) / 16;            // 13 or 9
    const int NTD = (NT * 16) << sh;
    const int total = NTD + 65;
    const int o = blockIdx.x * 256 + threadIdx.x;
    if (o >= total) return;
    const int s3 = 3 * D;
    const float sc = rsqrtf((float)D);
    if (o < NTD) {
        const int n = o >> sh, k = o & (D - 1);
        float val = 0.f;
        if (n < D) {
            const float* a = wqkv + (size_t)k * s3;
            const float* b = wqkv + (size_t)n * s3 + D;
            float s = 0.f;
            for (int m = 0; m < D; ++m) s += a[m] * b[m];
            val = s * sc;
        } else if (n < D + 64) {
            const int j = n - D;
            const float* a = wqkv + (size_t)k * s3 + 2 * D;
            float s = 0.f;
            for (int m = 0; m < D; ++m) s += a[m] * wo[m * 64 + j];
            val = s;
        } else if (n == D + 64) {
            const float* a = wqkv + (size_t)k * s3;
            float s = 0.f;
            for (int m = 0; m < D; ++m) s += a[m] * bqkv[D + m];
            val = s * sc;
        } else if (n == D + 65) {
            const float* a = wqkv + (size_t)k * s3 + D;
            float s = 0.f;
            for (int m = 0; m < D; ++m) s += a[m] * bqkv[m];
            val = s * sc;
        }
        wT[o] = (f16)val;
    } else if (o < NTD + 64) {
        const int j = o - NTD;
        float s = 0.f;
        for (int m = 0; m < D; ++m) s += bqkv[2 * D + m] * wo[m * 64 + j];
        coAll[g * 64 + j] = s + bo[j];
    } else {
        float s = 0.f;
        for (int m = 0; m < D; ++m) s += bqkv[m] * bqkv[D + m];
        cAll[g] = s * sc;
    }
}

// wiT[n][k] = (f16) wi[k][n]  (wi is [768][256])
__global__ __launch_bounds__(256) void pk_wit(const float* __restrict__ wi, f16* __restrict__ wiT)
{
    int o = blockIdx.x * 256 + threadIdx.x;    // 196608 outputs
    int n = o / 768, k = o - n * 768;
    wiT[o] = (f16)wi[k * 256 + n];
}

// =============== fused per-group attention ===============
template<int D>
__device__ __forceinline__ void do_group(
    const float* __restrict__ words, const f16* __restrict__ wT,
    const float* __restrict__ co_g, const float* __restrict__ cAll, int gidx,
    f16* __restrict__ flat, int b0, int start, int gbase, int t,
    f16 (&Xs)[96][136], f16 (&Zs)[96][136], f16 (&Zvo)[96][72],
    float (&xuw)[96][2], float (&Sc)[288])
{
    constexpr int KST = D / 32;        // mfma K-steps
    constexpr int NT  = (D + 81) / 16; // col tiles: 13 (D=128) / 9 (D=64)
    constexpr int F4  = D / 4;         // float4 per staged row
    constexpr int NLD = 96 * F4 / 512; // 6 or 3 loads/thread

    const int wv = t >> 6, lane = t & 63;
    const int lrow = lane & 15, lk = lane >> 4;
    const int wr = wv >> 2, wc = wv & 3;   // 2 row-groups x 4 col-sets

    // ---- stage X (issue all loads, then convert+write) ----
    {
        float4 v[NLD];
        const int r0 = t / F4, c4 = t - r0 * F4;
        #pragma unroll
        for (int i = 0; i < NLD; ++i) {
            int r = r0 + i * (512 / F4);
            v[i] = *(const float4*)&words[(size_t)(b0 * 3 + r) * 384 + start + c4 * 4];
        }
        #pragma unroll
        for (int i = 0; i < NLD; ++i) {
            int r = r0 + i * (512 / F4);
            half4 h; h[0] = (f16)v[i].x; h[1] = (f16)v[i].y; h[2] = (f16)v[i].z; h[3] = (f16)v[i].w;
            *(half4*)&Xs[r][c4 * 4] = h;
        }
    }
    __syncthreads();

    // ---- phase A: Zfull = X @ [A | Wvo | u | w] ----
    {
        f32x4 acc[3][4];
        #pragma unroll
        for (int rt = 0; rt < 3; ++rt)
            #pragma unroll
            for (int ci = 0; ci < 4; ++ci) acc[rt][ci] = f32x4{0.f, 0.f, 0.f, 0.f};

        const f16* wbase = wT + (size_t)lrow * D + lk * 8;
        half8 bA[4], bB[4];

#define LOADB(BUF, KK)                                                          \
        { _Pragma("unroll")                                                     \
          for (int ci = 0; ci < 4; ++ci) {                                      \
              int ct = wc + ci * 4;                                             \
              if (ct < NT) BUF[ci] = *(const half8*)&wbase[(size_t)ct * 16 * D + (KK) * 32]; \
          } }
#define MSTEP(BUF, KK)                                                          \
        { half8 a0 = *(const half8*)&Xs[wr * 48 +  0 + lrow][(KK) * 32 + lk * 8]; \
          half8 a1 = *(const half8*)&Xs[wr * 48 + 16 + lrow][(KK) * 32 + lk * 8]; \
          half8 a2 = *(const half8*)&Xs[wr * 48 + 32 + lrow][(KK) * 32 + lk * 8]; \
          _Pragma("unroll")                                                     \
          for (int ci = 0; ci < 4; ++ci) {                                      \
              int ct = wc + ci * 4;                                             \
              if (ct < NT) {                                                    \
                  acc[0][ci] = __builtin_amdgcn_mfma_f32_16x16x32_f16(a0, BUF[ci], acc[0][ci], 0, 0, 0); \
                  acc[1][ci] = __builtin_amdgcn_mfma_f32_16x16x32_f16(a1, BUF[ci], acc[1][ci], 0, 0, 0); \
                  acc[2][ci] = __builtin_amdgcn_mfma_f32_16x16x32_f16(a2, BUF[ci], acc[2][ci], 0, 0, 0); \
              } } }

        LOADB(bA, 0)
        #pragma unroll
        for (int kp = 0; kp < KST / 2; ++kp) {
            LOADB(bB, 2 * kp + 1)
            MSTEP(bA, 2 * kp)
            if (2 * kp + 2 < KST) LOADB(bA, 2 * kp + 2)
            MSTEP(bB, 2 * kp + 1)
        }
#undef LOADB
#undef MSTEP

        // write-out: Z_A / Zvo / xu,xw
        #pragma unroll
        for (int ci = 0; ci < 4; ++ci) {
            int ct = wc + ci * 4;
            if (ct >= NT) continue;
            int n0 = ct * 16;
            if (n0 + 16 <= D) {
                #pragma unroll
                for (int rt = 0; rt < 3; ++rt)
                    #pragma unroll
                    for (int r = 0; r < 4; ++r)
                        Zs[wr * 48 + rt * 16 + lk * 4 + r][n0 + lrow] = (f16)acc[rt][ci][r];
            } else if (n0 < D + 64) {
                #pragma unroll
                for (int rt = 0; rt < 3; ++rt)
                    #pragma unroll
                    for (int r = 0; r < 4; ++r)
                        Zvo[wr * 48 + rt * 16 + lk * 4 + r][n0 - D + lrow] = (f16)acc[rt][ci][r];
            } else {
                if (lrow < 2) {
                    #pragma unroll
                    for (int rt = 0; rt < 3; ++rt)
                        #pragma unroll
                        for (int r = 0; r < 4; ++r)
                            xuw[wr * 48 + rt * 16 + lk * 4 + r][lrow] = acc[rt][ci][r];
                }
            }
        }
    }
    __syncthreads();

    // ---- scores: block-diag tiles of S = Z_A . X^T (+ bias terms) ----
    {
        const float cval = cAll[gidx];
        #pragma unroll
        for (int j = 0; j < 3; ++j) {
            int tt = wc + j * 4;
            if (tt < 9) {
                int rt = tt / 3, ct = tt - rt * 3;
                f32x4 s = f32x4{0.f, 0.f, 0.f, 0.f};
                #pragma unroll
                for (int kk = 0; kk < KST; ++kk) {
                    half8 a = *(const half8*)&Zs[wr * 48 + rt * 16 + lrow][kk * 32 + lk * 8];
                    half8 b = *(const half8*)&Xs[wr * 48 + ct * 16 + lrow][kk * 32 + lk * 8];
                    s = __builtin_amdgcn_mfma_f32_16x16x32_f16(a, b, s, 0, 0, 0);
                }
                #pragma unroll
                for (int r = 0; r < 4; ++r) {
                    int r1 = rt * 16 + lk * 4 + r;
                    int r2 = ct * 16 + lrow;
                    int b1 = r1 / 3, w1 = r1 - b1 * 3;
                    int b2 = r2 / 3, w2 = r2 - b2 * 3;
                    if (b1 == b2)
                        Sc[(wr * 16 + b1) * 9 + w1 * 3 + w2] =
                            s[r] + xuw[wr * 48 + r1][0] + xuw[wr * 48 + r2][1] + cval;
                }
            }
        }
    }
    __syncthreads();

    // ---- epilogue: inline softmax + P.Zvo + co, relu, store flat ----
    for (int i = t; i < 768; i += 512) {
        int b = i / 24, rem = i - b * 24;
        int w1 = rem >> 3, c8 = rem & 7;
        float s0 = Sc[b * 9 + w1 * 3 + 0];
        float s1 = Sc[b * 9 + w1 * 3 + 1];
        float s2 = Sc[b * 9 + w1 * 3 + 2];
        float m = fmaxf(s0, fmaxf(s1, s2));
        float e0 = __expf(s0 - m), e1 = __expf(s1 - m), e2 = __expf(s2 - m);
        float inv = 1.0f / (e0 + e1 + e2);
        half8 z0 = *(const half8*)&Zvo[b * 3 + 0][c8 * 8];
        half8 z1 = *(const half8*)&Zvo[b * 3 + 1][c8 * 8];
        half8 z2 = *(const half8*)&Zvo[b * 3 + 2][c8 * 8];
        half8 o;
        #pragma unroll
        for (int jj = 0; jj < 8; ++jj) {
            float v = (e0 * (float)z0[jj] + e1 * (float)z1[jj] + e2 * (float)z2[jj]) * inv
                      + co_g[c8 * 8 + jj];
            o[jj] = (f16)fmaxf(v, 0.f);
        }
        *(half8*)&flat[(size_t)(b0 + b) * 768 + gbase + w1 * 64 + c8 * 8] = o;
    }
    __syncthreads();
}

__global__ __launch_bounds__(512, 4) void k1_all(
    const float* __restrict__ words,
    const f16* __restrict__ wT0, const f16* __restrict__ wT1,
    const f16* __restrict__ wT2, const f16* __restrict__ wT3,
    const float* __restrict__ coAll, const float* __restrict__ cAll,
    f16* __restrict__ flat)
{
    __shared__ f16 Xs[96][136];
    __shared__ f16 Zs[96][136];
    __shared__ f16 Zvo[96][72];
    __shared__ float xuw[96][2];
    __shared__ float Sc[288];
    __shared__ float co_s[256];

    const int t = threadIdx.x;
    const int b0 = blockIdx.x * 32;
    if (t < 256) co_s[t] = coAll[t];

    do_group<128>(words, wT0, &co_s[0],   cAll, 0, flat, b0, 0,   0,   t, Xs, Zs, Zvo, xuw, Sc);
    do_group<64> (words, wT1, &co_s[64],  cAll, 1, flat, b0, 128, 192, t, Xs, Zs, Zvo, xuw, Sc);
    do_group<128>(words, wT2, &co_s[128], cAll, 2, flat, b0, 192, 384, t, Xs, Zs, Zvo, xuw, Sc);
    do_group<64> (words, wT3, &co_s[192], cAll, 3, flat, b0, 320, 576, t, Xs, Zs, Zvo, xuw, Sc);
}

// =============== kernel 2: MLP (flat @ wi -> relu -> @ wout) ===============
__global__ __launch_bounds__(512) void k2_mlp(
    const f16* __restrict__ flat, const f16* __restrict__ wiT,
    const float* __restrict__ bi, const float* __restrict__ wout, const float* __restrict__ bout,
    float* __restrict__ out)
{
    __shared__ f16 Xs[128][72];
    __shared__ f16 Wsh[256][72];
    __shared__ float part[128][2];
    __shared__ float bi_l[256], wo_l[256];

    const int t = threadIdx.x;
    const int b0 = blockIdx.x * 128;
    if (t < 256) { bi_l[t] = bi[t]; wo_l[t] = wout[t]; }

    const int wv = t >> 6, lane = t & 63;
    const int wr = wv >> 1, wc = wv & 1;
    const int lrow = lane & 15, lk = lane >> 4;

    f32x4 acc[2][8];
    #pragma unroll
    for (int i = 0; i < 2; ++i)
        #pragma unroll
        for (int j = 0; j < 8; ++j) acc[i][j] = f32x4{0.f, 0.f, 0.f, 0.f};

    for (int kc = 0; kc < 12; ++kc) {
        __syncthreads();
        for (int u = t; u < 1024; u += 512) {
            int r = u >> 3, c8 = u & 7;
            *(half8*)&Xs[r][c8 * 8] = *(const half8*)&flat[(size_t)(b0 + r) * 768 + kc * 64 + c8 * 8];
        }
        for (int u = t; u < 2048; u += 512) {
            int n = u >> 3, c8 = u & 7;
            *(half8*)&Wsh[n][c8 * 8] = *(const half8*)&wiT[(size_t)n * 768 + kc * 64 + c8 * 8];
        }
        __syncthreads();
        #pragma unroll
        for (int ks = 0; ks < 2; ++ks) {
            half8 a0 = *(const half8*)&Xs[wr * 32 + lrow][ks * 32 + lk * 8];
            half8 a1 = *(const half8*)&Xs[wr * 32 + 16 + lrow][ks * 32 + lk * 8];
            #pragma unroll
            for (int ct = 0; ct < 8; ++ct) {
                half8 b = *(const half8*)&Wsh[wc * 128 + ct * 16 + lrow][ks * 32 + lk * 8];
                acc[0][ct] = __builtin_amdgcn_mfma_f32_16x16x32_f16(a0, b, acc[0][ct], 0, 0, 0);
                acc[1][ct] = __builtin_amdgcn_mfma_f32_16x16x32_f16(a1, b, acc[1][ct], 0, 0, 0);
            }
        }
    }

    float bo0 = bout[0];
    #pragma unroll
    for (int rt = 0; rt < 2; ++rt) {
        #pragma unroll
        for (int r = 0; r < 4; ++r) {
            float s = 0.f;
            #pragma unroll
            for (int ct = 0; ct < 8; ++ct) {
                int col = wc * 128 + ct * 16 + lrow;
                float v = acc[rt][ct][r] + bi_l[col];
                v = fmaxf(v, 0.f);
                s += v * wo_l[col];
            }
            s += __shfl_xor(s, 1, 64); s += __shfl_xor(s, 2, 64);
            s += __shfl_xor(s, 4, 64); s += __shfl_xor(s, 8, 64);
            if (lrow == 0) part[wr * 32 + rt * 16 + lk * 4 + r][wc] = s;
        }
    }
    __syncthreads();
    if (t < 128) out[b0 + t] = part[t][0] + part[t][1] + bo0;
}

// =============== host launcher ===============
extern "C" void kernel_launch(void* const* d_in, const int* in_sizes, int n_in,
                              void* d_out, int out_size, void* d_ws, size_t ws_size,
                              hipStream_t stream)
{
    const float* words = (const float*)d_in[0];
    const float* wq[4] = {(const float*)d_in[1], (const float*)d_in[5], (const float*)d_in[9],  (const float*)d_in[13]};
    const float* bq[4] = {(const float*)d_in[2], (const float*)d_in[6], (const float*)d_in[10], (const float*)d_in[14]};
    const float* wo[4] = {(const float*)d_in[3], (const float*)d_in[7], (const float*)d_in[11], (const float*)d_in[15]};
    const float* bo[4] = {(const float*)d_in[4], (const float*)d_in[8], (const float*)d_in[12], (const float*)d_in[16]};
    const float* wi   = (const float*)d_in[17];
    const float* bi   = (const float*)d_in[18];
    const float* wout = (const float*)d_in[19];
    const float* bout = (const float*)d_in[20];

    char* ws = (char*)d_ws;
    f16*   flat = (f16*)(ws + OFF_FLAT);
    f16*   wiT  = (f16*)(ws + OFF_WIT);
    f16*   wT0  = (f16*)(ws + OFF_WT0);
    f16*   wT1  = (f16*)(ws + OFF_WT1);
    f16*   wT2  = (f16*)(ws + OFF_WT2);
    f16*   wT3  = (f16*)(ws + OFF_WT3);
    float* coA  = (float*)(ws + OFF_CO);
    float* cA   = (float*)(ws + OFF_C);

    pk_fuse<<<dim3(105, 4), 256, 0, stream>>>(
        wq[0], bq[0], wo[0], bo[0], wq[1], bq[1], wo[1], bo[1],
        wq[2], bq[2], wo[2], bo[2], wq[3], bq[3], wo[3], bo[3],
        wT0, wT1, wT2, wT3, coA, cA);
    pk_wit<<<768, 256, 0, stream>>>(wi, wiT);

    k1_all<<<2048, 512, 0, stream>>>(words, wT0, wT1, wT2, wT3, coA, cA, flat);

    k2_mlp<<<512, 512, 0, stream>>>(flat, wiT, bi, wout, bout, (float*)d_out);
}

// Round 3
// 238.093 us; speedup vs baseline: 1.4086x; 1.4086x over previous
//
#include <hip/hip_runtime.h>

typedef _Float16 f16;
typedef _Float16 half8 __attribute__((ext_vector_type(8)));
typedef _Float16 half4 __attribute__((ext_vector_type(4)));
typedef float f32x4 __attribute__((ext_vector_type(4)));

#define BTOT 65536

// ---------------- workspace layout (bytes) ----------------
static const size_t OFF_FLAT = 0;
static const size_t SZ_FLAT  = (size_t)BTOT * 768 * 2;        // f16 [B][768]
static const size_t OFF_WIT  = OFF_FLAT + SZ_FLAT;            // f16 [256][768]
static const size_t SZ_WIT   = (size_t)256 * 768 * 2;
static const size_t SZ_WT128 = (size_t)208 * 128 * 2;         // 13 tiles * 16 rows
static const size_t SZ_WT64  = (size_t)144 * 64 * 2;          // 9 tiles * 16 rows
static const size_t OFF_WT0  = OFF_WIT + SZ_WIT;
static const size_t OFF_WT1  = OFF_WT0 + SZ_WT128;
static const size_t OFF_WT2  = OFF_WT1 + SZ_WT64;
static const size_t OFF_WT3  = OFF_WT2 + SZ_WT128;
static const size_t OFF_CO   = OFF_WT3 + SZ_WT64;             // f32 [4][64]
static const size_t OFF_C    = OFF_CO + 256 * 4;              // f32 [4]

// =============== weight fusion: wT[n][k] (f16), co, c ===============
__global__ __launch_bounds__(256) void pk_fuse(
    const float* __restrict__ wq0, const float* __restrict__ bq0, const float* __restrict__ wo0, const float* __restrict__ bo0,
    const float* __restrict__ wq1, const float* __restrict__ bq1, const float* __restrict__ wo1, const float* __restrict__ bo1,
    const float* __restrict__ wq2, const float* __restrict__ bq2, const float* __restrict__ wo2, const float* __restrict__ bo2,
    const float* __restrict__ wq3, const float* __restrict__ bq3, const float* __restrict__ wo3, const float* __restrict__ bo3,
    f16* __restrict__ wT0, f16* __restrict__ wT1, f16* __restrict__ wT2, f16* __restrict__ wT3,
    float* __restrict__ coAll, float* __restrict__ cAll)
{
    const int g = blockIdx.y;
    const float* wqkv; const float* bqkv; const float* wo; const float* bo; f16* wT; int D;
    switch (g) {
        case 0:  wqkv = wq0; bqkv = bq0; wo = wo0; bo = bo0; wT = wT0; D = 128; break;
        case 1:  wqkv = wq1; bqkv = bq1; wo = wo1; bo = bo1; wT = wT1; D = 64;  break;
        case 2:  wqkv = wq2; bqkv = bq2; wo = wo2; bo = bo2; wT = wT2; D = 128; break;
        default: wqkv = wq3; bqkv = bq3; wo = wo3; bo = bo3; wT = wT3; D = 64;  break;
    }
    const int sh = (D == 128) ? 7 : 6;
    const int NT = (D + 81) / 16;            // 13 or 9
    const int NTD = (NT * 16) << sh;
    const int total = NTD + 65;
    const int o = blockIdx.x * 256 + threadIdx.x;
    if (o >= total) return;
    const int s3 = 3 * D;
    const float sc = rsqrtf((float)D);
    if (o < NTD) {
        const int n = o >> sh, k = o & (D - 1);
        float val = 0.f;
        if (n < D) {
            const float* a = wqkv + (size_t)k * s3;
            const float* b = wqkv + (size_t)n * s3 + D;
            float s = 0.f;
            for (int m = 0; m < D; ++m) s += a[m] * b[m];
            val = s * sc;
        } else if (n < D + 64) {
            const int j = n - D;
            const float* a = wqkv + (size_t)k * s3 + 2 * D;
            float s = 0.f;
            for (int m = 0; m < D; ++m) s += a[m] * wo[m * 64 + j];
            val = s;
        } else if (n == D + 64) {
            const float* a = wqkv + (size_t)k * s3;
            float s = 0.f;
            for (int m = 0; m < D; ++m) s += a[m] * bqkv[D + m];
            val = s * sc;
        } else if (n == D + 65) {
            const float* a = wqkv + (size_t)k * s3 + D;
            float s = 0.f;
            for (int m = 0; m < D; ++m) s += a[m] * bqkv[m];
            val = s * sc;
        }
        wT[o] = (f16)val;
    } else if (o < NTD + 64) {
        const int j = o - NTD;
        float s = 0.f;
        for (int m = 0; m < D; ++m) s += bqkv[2 * D + m] * wo[m * 64 + j];
        coAll[g * 64 + j] = s + bo[j];
    } else {
        float s = 0.f;
        for (int m = 0; m < D; ++m) s += bqkv[m] * bqkv[D + m];
        cAll[g] = s * sc;
    }
}

// wiT[n][k] = (f16) wi[k][n]  (wi is [768][256])
__global__ __launch_bounds__(256) void pk_wit(const float* __restrict__ wi, f16* __restrict__ wiT)
{
    int o = blockIdx.x * 256 + threadIdx.x;    // 196608 outputs
    int n = o / 768, k = o - n * 768;
    wiT[o] = (f16)wi[k * 256 + n];
}

// =============== fused per-group attention (16 batches / 48 rows / 4 waves) ===============
template<int D>
__device__ __forceinline__ void do_group(
    const float* __restrict__ words, const f16* __restrict__ wT,
    const float* __restrict__ co_g, const float* __restrict__ cAll, int gidx,
    f16* __restrict__ flat, int b0, int start, int gbase, int t, char* smem)
{
    constexpr int KST = D / 32;        // mfma K-steps
    constexpr int NT  = (D + 81) / 16; // col tiles: 13 (D=128) / 9 (D=64)
    constexpr int XP  = D + 8;         // padded LDS row
    constexpr int F4  = D / 4;         // float4 per staged row
    constexpr int NLD = 48 * F4 / 256; // 6 or 3 loads/thread

    f16 (*Xs)[XP]   = (f16(*)[XP])(smem);
    f16 (*Zs)[XP]   = (f16(*)[XP])(smem + (size_t)48 * XP * 2);
    f16 (*Zvo)[72]  = (f16(*)[72])(smem + (size_t)96 * XP * 2);
    float* Sc       = (float*)(smem + (size_t)96 * XP * 2 + 48 * 72 * 2);  // [144]
    float (*xuw)[2] = (float(*)[2])(Sc + 144);                             // [48][2]

    const int wc = t >> 6, lane = t & 63;
    const int lrow = lane & 15, lk = lane >> 4;

    // ---- stage X (issue all loads, then convert+write) ----
    {
        float4 v[NLD];
        const int r0 = t / F4, c4 = t - r0 * F4;
        #pragma unroll
        for (int i = 0; i < NLD; ++i) {
            int r = r0 + i * (256 / F4);
            v[i] = *(const float4*)&words[(size_t)(b0 * 3 + r) * 384 + start + c4 * 4];
        }
        #pragma unroll
        for (int i = 0; i < NLD; ++i) {
            int r = r0 + i * (256 / F4);
            half4 h; h[0] = (f16)v[i].x; h[1] = (f16)v[i].y; h[2] = (f16)v[i].z; h[3] = (f16)v[i].w;
            *(half4*)&Xs[r][c4 * 4] = h;
        }
    }
    __syncthreads();

    // ---- phase A: Zfull = X @ [A | Wvo | u | w] ----
    {
        f32x4 acc[3][4];
        #pragma unroll
        for (int rt = 0; rt < 3; ++rt)
            #pragma unroll
            for (int ci = 0; ci < 4; ++ci) acc[rt][ci] = f32x4{0.f, 0.f, 0.f, 0.f};

        const f16* wbase = wT + (size_t)lrow * D + lk * 8;
        half8 bA[4], bB[4];

#define LOADB(BUF, KK)                                                          \
        { _Pragma("unroll")                                                     \
          for (int ci = 0; ci < 4; ++ci) {                                      \
              int ct = wc + ci * 4;                                             \
              if (ct < NT) BUF[ci] = *(const half8*)&wbase[(size_t)ct * 16 * D + (KK) * 32]; \
          } }
#define MSTEP(BUF, KK)                                                          \
        { half8 a0 = *(const half8*)&Xs[ 0 + lrow][(KK) * 32 + lk * 8];         \
          half8 a1 = *(const half8*)&Xs[16 + lrow][(KK) * 32 + lk * 8];         \
          half8 a2 = *(const half8*)&Xs[32 + lrow][(KK) * 32 + lk * 8];         \
          _Pragma("unroll")                                                     \
          for (int ci = 0; ci < 4; ++ci) {                                      \
              int ct = wc + ci * 4;                                             \
              if (ct < NT) {                                                    \
                  acc[0][ci] = __builtin_amdgcn_mfma_f32_16x16x32_f16(a0, BUF[ci], acc[0][ci], 0, 0, 0); \
                  acc[1][ci] = __builtin_amdgcn_mfma_f32_16x16x32_f16(a1, BUF[ci], acc[1][ci], 0, 0, 0); \
                  acc[2][ci] = __builtin_amdgcn_mfma_f32_16x16x32_f16(a2, BUF[ci], acc[2][ci], 0, 0, 0); \
              } } }

        LOADB(bA, 0)
        #pragma unroll
        for (int kp = 0; kp < KST / 2; ++kp) {
            LOADB(bB, 2 * kp + 1)
            MSTEP(bA, 2 * kp)
            if (2 * kp + 2 < KST) LOADB(bA, 2 * kp + 2)
            MSTEP(bB, 2 * kp + 1)
        }
#undef LOADB
#undef MSTEP

        // write-out: Z_A / Zvo / xu,xw
        #pragma unroll
        for (int ci = 0; ci < 4; ++ci) {
            int ct = wc + ci * 4;
            if (ct >= NT) continue;
            int n0 = ct * 16;
            if (n0 + 16 <= D) {
                #pragma unroll
                for (int rt = 0; rt < 3; ++rt)
                    #pragma unroll
                    for (int r = 0; r < 4; ++r)
                        Zs[rt * 16 + lk * 4 + r][n0 + lrow] = (f16)acc[rt][ci][r];
            } else if (n0 < D + 64) {
                #pragma unroll
                for (int rt = 0; rt < 3; ++rt)
                    #pragma unroll
                    for (int r = 0; r < 4; ++r)
                        Zvo[rt * 16 + lk * 4 + r][n0 - D + lrow] = (f16)acc[rt][ci][r];
            } else {
                if (lrow < 2) {
                    #pragma unroll
                    for (int rt = 0; rt < 3; ++rt)
                        #pragma unroll
                        for (int r = 0; r < 4; ++r)
                            xuw[rt * 16 + lk * 4 + r][lrow] = acc[rt][ci][r];
                }
            }
        }
    }
    __syncthreads();

    // ---- scores: block-diag tiles of S = Z_A . X^T (+ bias terms) ----
    {
        const float cval = cAll[gidx];
        #pragma unroll
        for (int j = 0; j < 3; ++j) {
            int tt = wc + j * 4;
            if (tt < 9) {
                int rt = tt / 3, ct = tt - rt * 3;
                f32x4 s = f32x4{0.f, 0.f, 0.f, 0.f};
                #pragma unroll
                for (int kk = 0; kk < KST; ++kk) {
                    half8 a = *(const half8*)&Zs[rt * 16 + lrow][kk * 32 + lk * 8];
                    half8 b = *(const half8*)&Xs[ct * 16 + lrow][kk * 32 + lk * 8];
                    s = __builtin_amdgcn_mfma_f32_16x16x32_f16(a, b, s, 0, 0, 0);
                }
                #pragma unroll
                for (int r = 0; r < 4; ++r) {
                    int r1 = rt * 16 + lk * 4 + r;
                    int r2 = ct * 16 + lrow;
                    int b1 = r1 / 3, w1 = r1 - b1 * 3;
                    int b2 = r2 / 3, w2 = r2 - b2 * 3;
                    if (b1 == b2)
                        Sc[b1 * 9 + w1 * 3 + w2] =
                            s[r] + xuw[r1][0] + xuw[r2][1] + cval;
                }
            }
        }
    }
    __syncthreads();

    // ---- epilogue: inline softmax + P.Zvo + co, relu, store flat ----
    for (int i = t; i < 384; i += 256) {
        int b = i / 24, rem = i - b * 24;
        int w1 = rem >> 3, c8 = rem & 7;
        float s0 = Sc[b * 9 + w1 * 3 + 0];
        float s1 = Sc[b * 9 + w1 * 3 + 1];
        float s2 = Sc[b * 9 + w1 * 3 + 2];
        float m = fmaxf(s0, fmaxf(s1, s2));
        float e0 = __expf(s0 - m), e1 = __expf(s1 - m), e2 = __expf(s2 - m);
        float inv = 1.0f / (e0 + e1 + e2);
        float4 cA4 = *(const float4*)&co_g[c8 * 8];
        float4 cB4 = *(const float4*)&co_g[c8 * 8 + 4];
        float cov[8] = {cA4.x, cA4.y, cA4.z, cA4.w, cB4.x, cB4.y, cB4.z, cB4.w};
        half8 z0 = *(const half8*)&Zvo[b * 3 + 0][c8 * 8];
        half8 z1 = *(const half8*)&Zvo[b * 3 + 1][c8 * 8];
        half8 z2 = *(const half8*)&Zvo[b * 3 + 2][c8 * 8];
        half8 o;
        #pragma unroll
        for (int jj = 0; jj < 8; ++jj) {
            float v = (e0 * (float)z0[jj] + e1 * (float)z1[jj] + e2 * (float)z2[jj]) * inv
                      + cov[jj];
            o[jj] = (f16)fmaxf(v, 0.f);
        }
        *(half8*)&flat[(size_t)(b0 + b) * 768 + gbase + w1 * 64 + c8 * 8] = o;
    }
}

__global__ __launch_bounds__(256, 4) void k1(
    const float* __restrict__ words,
    const f16* __restrict__ wT0, const f16* __restrict__ wT1,
    const f16* __restrict__ wT2, const f16* __restrict__ wT3,
    const float* __restrict__ coAll, const float* __restrict__ cAll,
    f16* __restrict__ flat)
{
    extern __shared__ char smem[];
    const int t = threadIdx.x;
    const int b0 = blockIdx.x * 16;
    const int g = blockIdx.y;
    if (g == 0)
        do_group<128>(words, wT0, coAll + 0,   cAll, 0, flat, b0, 0,   0,   t, smem);
    else if (g == 1)
        do_group<64> (words, wT1, coAll + 64,  cAll, 1, flat, b0, 128, 192, t, smem);
    else if (g == 2)
        do_group<128>(words, wT2, coAll + 128, cAll, 2, flat, b0, 192, 384, t, smem);
    else
        do_group<64> (words, wT3, coAll + 192, cAll, 3, flat, b0, 320, 576, t, smem);
}

// =============== kernel 2: MLP (flat @ wi -> relu -> @ wout) ===============
// 512 thr, M=128/block, A-frags direct from global flat, Wsh reg-prefetched
__global__ __launch_bounds__(512, 4) void k2_mlp(
    const f16* __restrict__ flat, const f16* __restrict__ wiT,
    const float* __restrict__ bi, const float* __restrict__ wout, const float* __restrict__ bout,
    float* __restrict__ out)
{
    __shared__ f16 Wsh[256][72];
    __shared__ float part[128][2];
    __shared__ float bi_l[256], wo_l[256];

    const int t = threadIdx.x;
    const int b0 = blockIdx.x * 128;
    if (t < 256) { bi_l[t] = bi[t]; wo_l[t] = wout[t]; }

    const int wv = t >> 6, lane = t & 63;
    const int wr = wv >> 1, wc = wv & 1;
    const int lrow = lane & 15, lk = lane >> 4;

    const int pn = t >> 3, pc8 = t & 7;      // staging coords (1/4 of Wsh per j)
    half8 wreg[4];
    #pragma unroll
    for (int j = 0; j < 4; ++j)
        wreg[j] = *(const half8*)&wiT[(size_t)(pn + j * 64) * 768 + pc8 * 8];

    const f16* arow0 = flat + (size_t)(b0 + wr * 32 + lrow) * 768;
    const f16* arow1 = flat + (size_t)(b0 + wr * 32 + 16 + lrow) * 768;

    f32x4 acc[2][8];
    #pragma unroll
    for (int i = 0; i < 2; ++i)
        #pragma unroll
        for (int j = 0; j < 8; ++j) acc[i][j] = f32x4{0.f, 0.f, 0.f, 0.f};

    for (int kc = 0; kc < 12; ++kc) {
        #pragma unroll
        for (int j = 0; j < 4; ++j)
            *(half8*)&Wsh[pn + j * 64][pc8 * 8] = wreg[j];
        __syncthreads();
        if (kc + 1 < 12) {
            #pragma unroll
            for (int j = 0; j < 4; ++j)
                wreg[j] = *(const half8*)&wiT[(size_t)(pn + j * 64) * 768 + (kc + 1) * 64 + pc8 * 8];
        }
        #pragma unroll
        for (int ks = 0; ks < 2; ++ks) {
            half8 a0 = *(const half8*)&arow0[kc * 64 + ks * 32 + lk * 8];
            half8 a1 = *(const half8*)&arow1[kc * 64 + ks * 32 + lk * 8];
            #pragma unroll
            for (int ct = 0; ct < 8; ++ct) {
                half8 b = *(const half8*)&Wsh[wc * 128 + ct * 16 + lrow][ks * 32 + lk * 8];
                acc[0][ct] = __builtin_amdgcn_mfma_f32_16x16x32_f16(a0, b, acc[0][ct], 0, 0, 0);
                acc[1][ct] = __builtin_amdgcn_mfma_f32_16x16x32_f16(a1, b, acc[1][ct], 0, 0, 0);
            }
        }
        __syncthreads();
    }

    float bo0 = bout[0];
    #pragma unroll
    for (int rt = 0; rt < 2; ++rt) {
        #pragma unroll
        for (int r = 0; r < 4; ++r) {
            float s = 0.f;
            #pragma unroll
            for (int ct = 0; ct < 8; ++ct) {
                int col = wc * 128 + ct * 16 + lrow;
                float v = acc[rt][ct][r] + bi_l[col];
                v = fmaxf(v, 0.f);
                s += v * wo_l[col];
            }
            s += __shfl_xor(s, 1, 64); s += __shfl_xor(s, 2, 64);
            s += __shfl_xor(s, 4, 64); s += __shfl_xor(s, 8, 64);
            if (lrow == 0) part[wr * 32 + rt * 16 + lk * 4 + r][wc] = s;
        }
    }
    __syncthreads();
    if (t < 128) out[b0 + t] = part[t][0] + part[t][1] + bo0;
}

// =============== host launcher ===============
extern "C" void kernel_launch(void* const* d_in, const int* in_sizes, int n_in,
                              void* d_out, int out_size, void* d_ws, size_t ws_size,
                              hipStream_t stream)
{
    const float* words = (const float*)d_in[0];
    const float* wq[4] = {(const float*)d_in[1], (const float*)d_in[5], (const float*)d_in[9],  (const float*)d_in[13]};
    const float* bq[4] = {(const float*)d_in[2], (const float*)d_in[6], (const float*)d_in[10], (const float*)d_in[14]};
    const float* wo[4] = {(const float*)d_in[3], (const float*)d_in[7], (const float*)d_in[11], (const float*)d_in[15]};
    const float* bo[4] = {(const float*)d_in[4], (const float*)d_in[8], (const float*)d_in[12], (const float*)d_in[16]};
    const float* wi   = (const float*)d_in[17];
    const float* bi   = (const float*)d_in[18];
    const float* wout = (const float*)d_in[19];
    const float* bout = (const float*)d_in[20];

    char* ws = (char*)d_ws;
    f16*   flat = (f16*)(ws + OFF_FLAT);
    f16*   wiT  = (f16*)(ws + OFF_WIT);
    f16*   wT0  = (f16*)(ws + OFF_WT0);
    f16*   wT1  = (f16*)(ws + OFF_WT1);
    f16*   wT2  = (f16*)(ws + OFF_WT2);
    f16*   wT3  = (f16*)(ws + OFF_WT3);
    float* coA  = (float*)(ws + OFF_CO);
    float* cA   = (float*)(ws + OFF_C);

    pk_fuse<<<dim3(105, 4), 256, 0, stream>>>(
        wq[0], bq[0], wo[0], bo[0], wq[1], bq[1], wo[1], bo[1],
        wq[2], bq[2], wo[2], bo[2], wq[3], bq[3], wo[3], bo[3],
        wT0, wT1, wT2, wT3, coA, cA);
    pk_wit<<<768, 256, 0, stream>>>(wi, wiT);

    // dynamic LDS: max over D variants = 96*136*2 + 48*72*2 + 144*4 + 48*2*4 = 34240 -> 34304
    k1<<<dim3(4096, 4), 256, 34304, stream>>>(words, wT0, wT1, wT2, wT3, coA, cA, flat);

    k2_mlp<<<512, 512, 0, stream>>>(flat, wiT, bi, wout, bout, (float*)d_out);
}